// Round 2
// baseline (2268.138 us; speedup 1.0000x reference)
//
#include <hip/hip_runtime.h>

constexpr int NU_ = 200000, NI_ = 100000;
constexpr int E_UB = 1000000, E_IU = 1000000, E_II = 500000;
constexpr int SXS = 136;  // LDS row stride (floats) for 128-wide rows, padded

// ================= CSR build =================
__global__ void deg_kernel(const int* __restrict__ dst, int E, int* __restrict__ deg) {
    int i = blockIdx.x * blockDim.x + threadIdx.x;
    if (i < E) atomicAdd(&deg[dst[i]], 1);
}

// per-block (1024 elems) sums
__global__ void scanA_kernel(const int* __restrict__ deg, int N, int* __restrict__ bsum) {
    __shared__ int s[256];
    int b = blockIdx.x, t = threadIdx.x;
    int base = b * 1024 + t * 4;
    int v = 0;
#pragma unroll
    for (int j = 0; j < 4; ++j) { int i = base + j; if (i < N) v += deg[i]; }
    s[t] = v; __syncthreads();
    for (int off = 1; off < 256; off <<= 1) {
        int x = (t >= off) ? s[t - off] : 0;
        __syncthreads();
        s[t] += x;
        __syncthreads();
    }
    if (t == 255) bsum[b] = s[255];
}

// single-block exclusive scan of block sums (nb <= 256)
__global__ void scanB_kernel(int* __restrict__ bsum, int nb) {
    __shared__ int s[256];
    int t = threadIdx.x;
    int v = (t < nb) ? bsum[t] : 0;
    s[t] = v; __syncthreads();
    for (int off = 1; off < 256; off <<= 1) {
        int x = (t >= off) ? s[t - off] : 0;
        __syncthreads();
        s[t] += x;
        __syncthreads();
    }
    if (t < nb) bsum[t] = s[t] - v;  // exclusive
}

__global__ void scanC_kernel(const int* __restrict__ deg, int N, const int* __restrict__ boff,
                             int* __restrict__ rp, int E) {
    __shared__ int s[256];
    int b = blockIdx.x, t = threadIdx.x;
    int base = b * 1024 + t * 4;
    int d[4]; int v = 0;
#pragma unroll
    for (int j = 0; j < 4; ++j) { int i = base + j; d[j] = (i < N) ? deg[i] : 0; v += d[j]; }
    s[t] = v; __syncthreads();
    for (int off = 1; off < 256; off <<= 1) {
        int x = (t >= off) ? s[t - off] : 0;
        __syncthreads();
        s[t] += x;
        __syncthreads();
    }
    int ex = boff[b] + s[t] - v;
#pragma unroll
    for (int j = 0; j < 4; ++j) { int i = base + j; if (i < N) rp[i] = ex; ex += d[j]; }
    if (b == 0 && t == 0) rp[N] = E;
}

__global__ void inv_from_deg(const int* __restrict__ deg, float* __restrict__ inv, int N) {
    int i = blockIdx.x * blockDim.x + threadIdx.x;
    if (i < N) inv[i] = 1.0f / fmaxf((float)deg[i], 1.0f);
}

__global__ void fill_kernel(const int* __restrict__ src, const int* __restrict__ dst, int E,
                            const int* __restrict__ rp, int* __restrict__ cur, int* __restrict__ col) {
    int e = blockIdx.x * blockDim.x + threadIdx.x;
    if (e < E) {
        int d = dst[e];
        int p = atomicAdd(&cur[d], 1);
        col[rp[d] + p] = src[e];
    }
}

// ================= fused update building blocks =================
// Block = 256 threads, 32 dst rows. Gather mapping: (r = tid>>3 row, cg = tid&7).
// GEMM mapping: (rg = tid>>5 -> rows rg*4..+4, cq = tid&31 -> cols cq*CPT..).

// mean-aggregate neighbors of 32 nodes into sX[32][SXS] (row length K)
template<int K>
__device__ inline void gather_avg(const float* __restrict__ xsrc,
                                  const int* __restrict__ rp, const int* __restrict__ col,
                                  const float* __restrict__ inv,
                                  int rowBase, int N, float* sX) {
    const int tid = threadIdx.x;
    const int r = tid >> 3, cg = tid & 7;
    constexpr int F4 = K / 32;  // float4s per thread
    float4 a[F4];
#pragma unroll
    for (int j = 0; j < F4; ++j) a[j] = make_float4(0.f, 0.f, 0.f, 0.f);
    const int node = rowBase + r;
    if (node < N) {
        int s = rp[node], e = rp[node + 1];
        for (; s < e; ++s) {
            int c = col[s];
            const float4* row = reinterpret_cast<const float4*>(xsrc + (size_t)c * K);
#pragma unroll
            for (int j = 0; j < F4; ++j) {
                float4 v = row[cg + 8 * j];
                a[j].x += v.x; a[j].y += v.y; a[j].z += v.z; a[j].w += v.w;
            }
        }
        float sc = inv[node];
#pragma unroll
        for (int j = 0; j < F4; ++j) { a[j].x *= sc; a[j].y *= sc; a[j].z *= sc; a[j].w *= sc; }
    }
    float4* so = reinterpret_cast<float4*>(sX + r * SXS);
#pragma unroll
    for (int j = 0; j < F4; ++j) so[cg + 8 * j] = a[j];
}

// stage 32 self rows into sX
template<int K>
__device__ inline void stage_self(const float* __restrict__ x, int rowBase, int N, float* sX) {
    const int tid = threadIdx.x;
    const int r = tid >> 3, cg = tid & 7;
    constexpr int F4 = K / 32;
    const int node = rowBase + r;
    float4* so = reinterpret_cast<float4*>(sX + r * SXS);
    if (node < N) {
        const float4* row = reinterpret_cast<const float4*>(x + (size_t)node * K);
#pragma unroll
        for (int j = 0; j < F4; ++j) so[cg + 8 * j] = row[cg + 8 * j];
    } else {
#pragma unroll
        for (int j = 0; j < F4; ++j) so[cg + 8 * j] = make_float4(0.f, 0.f, 0.f, 0.f);
    }
}

// acc[4][CPT] += sX[32][K] @ W[K][NCOL]   (W staged in 32-row LDS chunks)
template<int K, int NCOL>
__device__ inline void gemm_lds(const float* __restrict__ sX, const float* __restrict__ W,
                                float* sW, float* acc) {
    const int tid = threadIdx.x;
    const int rg = tid >> 5;
    const int cq = tid & 31;
    constexpr int CPT = NCOL / 32;
    for (int kc = 0; kc < K; kc += 32) {
        __syncthreads();
        const float4* Wg = reinterpret_cast<const float4*>(W + (size_t)kc * NCOL);
        float4* sW4 = reinterpret_cast<float4*>(sW);
#pragma unroll
        for (int j = 0; j < NCOL / 32; ++j) sW4[tid + j * 256] = Wg[tid + j * 256];
        __syncthreads();
#pragma unroll
        for (int k = 0; k < 32; ++k) {
            const float* wr = sW + k * NCOL + cq * CPT;
            float x0 = sX[(rg * 4 + 0) * SXS + kc + k];
            float x1 = sX[(rg * 4 + 1) * SXS + kc + k];
            float x2 = sX[(rg * 4 + 2) * SXS + kc + k];
            float x3 = sX[(rg * 4 + 3) * SXS + kc + k];
#pragma unroll
            for (int j = 0; j < CPT; ++j) {
                float w = wr[j];
                acc[0 * CPT + j] = fmaf(x0, w, acc[0 * CPT + j]);
                acc[1 * CPT + j] = fmaf(x1, w, acc[1 * CPT + j]);
                acc[2 * CPT + j] = fmaf(x2, w, acc[2 * CPT + j]);
                acc[3 * CPT + j] = fmaf(x3, w, acc[3 * CPT + j]);
            }
        }
    }
}

// ================= user update: out = relu(agg@Wl + self@Wr + b) =================
template<int KAGG, int KS>
__global__ __launch_bounds__(256) void user_kernel(
    const float* __restrict__ xagg, const int* __restrict__ rp, const int* __restrict__ col,
    const float* __restrict__ inv, const float* __restrict__ xself,
    const float* __restrict__ Wl, const float* __restrict__ Wr, const float* __restrict__ bias,
    float* __restrict__ out, int N) {
    __shared__ float sX[32 * SXS];
    __shared__ float sW[32 * 128];
    float acc[16];
    const int tid = threadIdx.x;
    const int rg = tid >> 5, cq = tid & 31;
    const int rowBase = blockIdx.x * 32;
#pragma unroll
    for (int i = 0; i < 4; ++i)
#pragma unroll
        for (int j = 0; j < 4; ++j) acc[i * 4 + j] = bias[cq * 4 + j];
    gather_avg<KAGG>(xagg, rp, col, inv, rowBase, N, sX);
    gemm_lds<KAGG, 128>(sX, Wl, sW, acc);
    __syncthreads();
    stage_self<KS>(xself, rowBase, N, sX);
    gemm_lds<KS, 128>(sX, Wr, sW, acc);
#pragma unroll
    for (int i = 0; i < 4; ++i) {
        int row = rowBase + rg * 4 + i;
        if (row < N) {
            float4 v;
            v.x = fmaxf(acc[i * 4 + 0], 0.f);
            v.y = fmaxf(acc[i * 4 + 1], 0.f);
            v.z = fmaxf(acc[i * 4 + 2], 0.f);
            v.w = fmaxf(acc[i * 4 + 3], 0.f);
            *reinterpret_cast<float4*>(out + (size_t)row * 128 + cq * 4) = v;
        }
    }
}

// ====== item update: out = relu(0.5*(aggA@WlA + aggB@WlB + self@(WrA)+self@(WrB) + bA + bB)) ======
template<int KA, int KB, int KS>
__global__ __launch_bounds__(256) void item_kernel(
    const float* __restrict__ xsrcA, const int* __restrict__ rpA, const int* __restrict__ colA,
    const float* __restrict__ invA,
    const float* __restrict__ WlA, const float* __restrict__ WrA, const float* __restrict__ bA,
    const float* __restrict__ xsrcB, const int* __restrict__ rpB, const int* __restrict__ colB,
    const float* __restrict__ invB,
    const float* __restrict__ WlB, const float* __restrict__ WrB, const float* __restrict__ bB,
    const float* __restrict__ xself, float* __restrict__ out, int N) {
    __shared__ float sX[32 * SXS];
    __shared__ float sW[32 * 128];
    float acc[16];
    const int tid = threadIdx.x;
    const int rg = tid >> 5, cq = tid & 31;
    const int rowBase = blockIdx.x * 32;
#pragma unroll
    for (int i = 0; i < 4; ++i)
#pragma unroll
        for (int j = 0; j < 4; ++j) acc[i * 4 + j] = bA[cq * 4 + j] + bB[cq * 4 + j];
    gather_avg<KA>(xsrcA, rpA, colA, invA, rowBase, N, sX);
    gemm_lds<KA, 128>(sX, WlA, sW, acc);
    __syncthreads();
    gather_avg<KB>(xsrcB, rpB, colB, invB, rowBase, N, sX);
    gemm_lds<KB, 128>(sX, WlB, sW, acc);
    __syncthreads();
    stage_self<KS>(xself, rowBase, N, sX);
    gemm_lds<KS, 128>(sX, WrA, sW, acc);
    gemm_lds<KS, 128>(sX, WrB, sW, acc);
#pragma unroll
    for (int i = 0; i < 4; ++i) {
        int row = rowBase + rg * 4 + i;
        if (row < N) {
            float4 v;
            v.x = fmaxf(0.5f * acc[i * 4 + 0], 0.f);
            v.y = fmaxf(0.5f * acc[i * 4 + 1], 0.f);
            v.z = fmaxf(0.5f * acc[i * 4 + 2], 0.f);
            v.w = fmaxf(0.5f * acc[i * 4 + 3], 0.f);
            *reinterpret_cast<float4*>(out + (size_t)row * 128 + cq * 4) = v;
        }
    }
}

// ================= final linear 128 -> 64 (no relu) =================
__global__ __launch_bounds__(256) void final_kernel(
    const float* __restrict__ x, const float* __restrict__ W, const float* __restrict__ bias,
    float* __restrict__ out, int N) {
    __shared__ float sX[32 * SXS];
    __shared__ float sW[32 * 64];
    float acc[8];
    const int tid = threadIdx.x;
    const int rg = tid >> 5, cq = tid & 31;
    const int rowBase = blockIdx.x * 32;
#pragma unroll
    for (int i = 0; i < 4; ++i)
#pragma unroll
        for (int j = 0; j < 2; ++j) acc[i * 2 + j] = bias[cq * 2 + j];
    stage_self<128>(x, rowBase, N, sX);
    gemm_lds<128, 64>(sX, W, sW, acc);
#pragma unroll
    for (int i = 0; i < 4; ++i) {
        int row = rowBase + rg * 4 + i;
        if (row < N) {
            float2 v;
            v.x = acc[i * 2 + 0];
            v.y = acc[i * 2 + 1];
            *reinterpret_cast<float2*>(out + (size_t)row * 64 + cq * 2) = v;
        }
    }
}

// ================= host =================
static void build_csr(const int* src, const int* dst, int E, int N,
                      int* deg, int* bsum, int* rp, int* col, float* inv, hipStream_t stream) {
    const int B = 256;
    hipMemsetAsync(deg, 0, (size_t)N * sizeof(int), stream);
    deg_kernel<<<(E + B - 1) / B, B, 0, stream>>>(dst, E, deg);
    int nb = (N + 1023) / 1024;
    scanA_kernel<<<nb, B, 0, stream>>>(deg, N, bsum);
    scanB_kernel<<<1, B, 0, stream>>>(bsum, nb);
    scanC_kernel<<<nb, B, 0, stream>>>(deg, N, bsum, rp, E);
    inv_from_deg<<<(N + B - 1) / B, B, 0, stream>>>(deg, inv, N);
    hipMemsetAsync(deg, 0, (size_t)N * sizeof(int), stream);  // reuse as cursor
    fill_kernel<<<(E + B - 1) / B, B, 0, stream>>>(src, dst, E, rp, deg, col);
}

extern "C" void kernel_launch(void* const* d_in, const int* in_sizes, int n_in,
                              void* d_out, int out_size, void* d_ws, size_t ws_size,
                              hipStream_t stream) {
    const float* x_user = (const float*)d_in[0];
    const float* x_item = (const float*)d_in[1];
    const int* ub_src = (const int*)d_in[2];
    const int* ub_dst = (const int*)d_in[3];
    const int* iu_src = (const int*)d_in[4];
    const int* iu_dst = (const int*)d_in[5];
    const int* ii_src = (const int*)d_in[6];
    const int* ii_dst = (const int*)d_in[7];
    const float* W1l_ub = (const float*)d_in[8];
    const float* W1r_ub = (const float*)d_in[9];
    const float* b1_ub = (const float*)d_in[10];
    const float* W1l_iu = (const float*)d_in[11];
    const float* W1r_iu = (const float*)d_in[12];
    const float* b1_iu = (const float*)d_in[13];
    const float* W1l_ii = (const float*)d_in[14];
    const float* W1r_ii = (const float*)d_in[15];
    const float* b1_ii = (const float*)d_in[16];
    const float* W23l = (const float*)d_in[17];
    const float* W23r = (const float*)d_in[18];
    const float* b23 = (const float*)d_in[19];
    const float* Wf_user = (const float*)d_in[20];
    const float* bf_user = (const float*)d_in[21];
    const float* Wf_item = (const float*)d_in[22];
    const float* bf_item = (const float*)d_in[23];

    // ---- workspace layout (~168 MB) ----
    char* p = (char*)d_ws;
    float* xu = (float*)p;            p += (size_t)NU_ * 128 * sizeof(float);
    float* xiA = (float*)p;           p += (size_t)NI_ * 128 * sizeof(float);
    float* inv_iu = (float*)p;        p += (size_t)NU_ * sizeof(float);
    float* inv_ub = (float*)p;        p += (size_t)NI_ * sizeof(float);
    float* inv_ii = (float*)p;        p += (size_t)NI_ * sizeof(float);
    int* rp_iu = (int*)p;             p += (size_t)(NU_ + 4) * sizeof(int);
    int* rp_ub = (int*)p;             p += (size_t)(NI_ + 4) * sizeof(int);
    int* rp_ii = (int*)p;             p += (size_t)(NI_ + 4) * sizeof(int);
    int* col_iu = (int*)p;            p += (size_t)E_IU * sizeof(int);
    int* col_ub = (int*)p;            p += (size_t)E_UB * sizeof(int);
    int* col_ii = (int*)p;            p += (size_t)E_II * sizeof(int);
    int* deg = (int*)p;               p += (size_t)NU_ * sizeof(int);
    int* bsum = (int*)p;              p += 256 * sizeof(int);
    // xi ping-pong buffer B lives in d_out (dead before final kernels write there)
    float* xiB = (float*)d_out;

    // ---- CSR build (per relation) ----
    build_csr(iu_src, iu_dst, E_IU, NU_, deg, bsum, rp_iu, col_iu, inv_iu, stream);
    build_csr(ub_src, ub_dst, E_UB, NI_, deg, bsum, rp_ub, col_ub, inv_ub, stream);
    build_csr(ii_src, ii_dst, E_II, NI_, deg, bsum, rp_ii, col_ii, inv_ii, stream);

    const int gU = NU_ / 32;  // 6250
    const int gI = NI_ / 32;  // 3125

    // ---- layer 1 (reads only inputs) ----
    item_kernel<64, 128, 128><<<gI, 256, 0, stream>>>(
        x_user, rp_ub, col_ub, inv_ub, W1l_ub, W1r_ub, b1_ub,
        x_item, rp_ii, col_ii, inv_ii, W1l_ii, W1r_ii, b1_ii,
        x_item, xiA, NI_);
    user_kernel<128, 64><<<gU, 256, 0, stream>>>(
        x_item, rp_iu, col_iu, inv_iu, x_user, W1l_iu, W1r_iu, b1_iu, xu, NU_);

    // ---- layers 2-3 ----
    for (int l = 0; l < 2; ++l) {
        const float* cur = (l == 0) ? xiA : xiB;
        float* nxt = (l == 0) ? xiB : xiA;
        const size_t WSZ = 128 * 128;
        const float* Wl_ub = W23l + (size_t)(l * 3 + 0) * WSZ;
        const float* Wr_ub = W23r + (size_t)(l * 3 + 0) * WSZ;
        const float* b_ub = b23 + (size_t)(l * 3 + 0) * 128;
        const float* Wl_iu = W23l + (size_t)(l * 3 + 1) * WSZ;
        const float* Wr_iu = W23r + (size_t)(l * 3 + 1) * WSZ;
        const float* b_iu = b23 + (size_t)(l * 3 + 1) * 128;
        const float* Wl_ii = W23l + (size_t)(l * 3 + 2) * WSZ;
        const float* Wr_ii = W23r + (size_t)(l * 3 + 2) * WSZ;
        const float* b_ii = b23 + (size_t)(l * 3 + 2) * 128;

        // item first (its ub-gather needs the pre-update xu)
        item_kernel<128, 128, 128><<<gI, 256, 0, stream>>>(
            xu, rp_ub, col_ub, inv_ub, Wl_ub, Wr_ub, b_ub,
            cur, rp_ii, col_ii, inv_ii, Wl_ii, Wr_ii, b_ii,
            cur, nxt, NI_);
        // user in-place (gathers from cur, self rows only within own block)
        user_kernel<128, 128><<<gU, 256, 0, stream>>>(
            cur, rp_iu, col_iu, inv_iu, xu, Wl_iu, Wr_iu, b_iu, xu, NU_);
    }

    // ---- final linear: user first (overwrites xiB region), item reads xiA ----
    float* out = (float*)d_out;
    final_kernel<<<gU, 256, 0, stream>>>(xu, Wf_user, bf_user, out, NU_);
    final_kernel<<<gI, 256, 0, stream>>>(xiA, Wf_item, bf_item, out + (size_t)NU_ * 64, NI_);
}